// Round 11
// baseline (1002.011 us; speedup 1.0000x reference)
//
#include <hip/hip_runtime.h>

// AttentionRNN: B=64, NUM=8, TC=64, H=128. bn=512 sequences.
// R11 = R9 (validated 458us) + software-pipelined phase D:
//   - chunk-0 weight loads issued after the A-barrier (hide under B+C)
//   - double-buffered wA[16]/wB[16], loads of chunk c+1 before FMAs of chunk c
//   - max-free softmax (|e|<=sum|v|~5, validated R5/R8/R10): one less barrier
// 256 thr/block, launch_bounds(256,1): no 128-VGPR cap (R9-proven), no spill.

#define OFF_U     0      // [64][64] att_u staging (prologue only)
#define OFF_XMRM  4096   // [mat][seq][384] = [2][2][384]
#define OFF_HST   5632   // [2][128]
#define OFF_HPP   5888   // [2][4][64]  h_part partials
#define OFF_HPART 6400   // [2][64]
#define OFF_XTV   6528   // [2][128]  x_t = a * x_col
#define OFF_VV    6784   // [64] att_v
#define OFF_RED   6848   // [16] softmax cross-wave scratch
#define LDS_FLOATS 6864

#define FMA4(ACC, W, S) do { (ACC).x += (W).x*(S); (ACC).y += (W).y*(S); \
                             (ACC).z += (W).z*(S); (ACC).w += (W).w*(S); } while(0)

// load 16 float4 weight rows of chunk cc (rows cc*16 .. cc*16+15)
#define LOADW(BUF, cc) do { \
    _Pragma("unroll") \
    for (int r_ = 0; r_ < 16; ++r_) \
        BUF[r_] = *(const float4*)(Wm + (size_t)((cc) * 16 + r_) * 384); \
} while (0)

// FMA chunk cc from BUF against both seqs' inputs (LDS broadcast reads)
#define FMACHUNK(BUF, cc) do { \
    const float* i0_ = lds + ivoff + (cc) * 16; \
    float4 iA0 = *(const float4*)(i0_); \
    float4 iA1 = *(const float4*)(i0_ + 4); \
    float4 iA2 = *(const float4*)(i0_ + 8); \
    float4 iA3 = *(const float4*)(i0_ + 12); \
    float4 iB0 = *(const float4*)(i0_ + 128); \
    float4 iB1 = *(const float4*)(i0_ + 132); \
    float4 iB2 = *(const float4*)(i0_ + 136); \
    float4 iB3 = *(const float4*)(i0_ + 140); \
    FMA4(a0, BUF[0],  iA0.x); FMA4(a1, BUF[0],  iB0.x); \
    FMA4(a0, BUF[1],  iA0.y); FMA4(a1, BUF[1],  iB0.y); \
    FMA4(a0, BUF[2],  iA0.z); FMA4(a1, BUF[2],  iB0.z); \
    FMA4(a0, BUF[3],  iA0.w); FMA4(a1, BUF[3],  iB0.w); \
    FMA4(a0, BUF[4],  iA1.x); FMA4(a1, BUF[4],  iB1.x); \
    FMA4(a0, BUF[5],  iA1.y); FMA4(a1, BUF[5],  iB1.y); \
    FMA4(a0, BUF[6],  iA1.z); FMA4(a1, BUF[6],  iB1.z); \
    FMA4(a0, BUF[7],  iA1.w); FMA4(a1, BUF[7],  iB1.w); \
    FMA4(a0, BUF[8],  iA2.x); FMA4(a1, BUF[8],  iB2.x); \
    FMA4(a0, BUF[9],  iA2.y); FMA4(a1, BUF[9],  iB2.y); \
    FMA4(a0, BUF[10], iA2.z); FMA4(a1, BUF[10], iB2.z); \
    FMA4(a0, BUF[11], iA2.w); FMA4(a1, BUF[11], iB2.w); \
    FMA4(a0, BUF[12], iA3.x); FMA4(a1, BUF[12], iB3.x); \
    FMA4(a0, BUF[13], iA3.y); FMA4(a1, BUF[13], iB3.y); \
    FMA4(a0, BUF[14], iA3.z); FMA4(a1, BUF[14], iB3.z); \
    FMA4(a0, BUF[15], iA3.w); FMA4(a1, BUF[15], iB3.w); \
} while (0)

__global__ __launch_bounds__(256, 1)
void attn_gru_kernel(const float* __restrict__ x, const float* __restrict__ att_v,
                     const float* __restrict__ att_w, const float* __restrict__ att_u,
                     const float* __restrict__ gk, const float* __restrict__ grk,
                     const float* __restrict__ gbias, float* __restrict__ out) {
    __shared__ float lds[LDS_FLOATS];
    const int tid = threadIdx.x;
    const int bn0 = blockIdx.x * 2;

    // stage U, v; init h = 0
    for (int i = tid; i < 4096; i += 256) lds[OFF_U + i] = att_u[i];
    if (tid < 64) lds[OFF_VV + tid] = att_v[tid];
    lds[OFF_HST + tid] = 0.0f;
    __syncthreads();

    const int seq = tid >> 7;   // 0/1 : which of the block's 2 sequences
    const int hh  = tid & 127;  // feature index
    const int s_  = tid & 63;
    const int hg  = tid >> 6;   // 0..3 (also wave id)

    // per-thread uproj[seq][hh][0..63] in registers
    float upreg[64];
    #pragma unroll
    for (int s2 = 0; s2 < 64; ++s2) upreg[s2] = 0.0f;
    {
        const float* xb = x + (size_t)(bn0 + seq) * 8192 + hh;
        for (int t = 0; t < 64; ++t) {
            float xv = xb[t * 128];                  // coalesced across hh lanes
            const float* Ur = lds + OFF_U + t * 64;  // broadcast reads
            #pragma unroll
            for (int s2 = 0; s2 < 64; ++s2) upreg[s2] += xv * Ur[s2];
        }
    }

    // att_w in registers: thread (hg, s_) owns W[hg*32+k][s_], k=0..31
    float wreg[32];
    #pragma unroll
    for (int k = 0; k < 32; ++k) wreg[k] = att_w[(hg * 32 + k) * 64 + s_];

    // GRU matvec (phase D) per-thread constants: quad of weight columns
    const int col4 = tid * 4;                 // 0..764 for tid<192
    const int dmat = (col4 >= 384) ? 1 : 0;   // 0 -> gru_kernel (x_t), 1 -> gru_rkernel (h)
    const int dj   = col4 - dmat * 384;       // multiple of 4
    const float* Wm = (dmat ? grk : gk) + dj;
    const int ivoff = dmat ? OFF_HST : OFF_XTV;
    float4 dbias = make_float4(0.f, 0.f, 0.f, 0.f);
    if (tid < 192) dbias = *(const float4*)(gbias + dmat * 384 + dj);

    __syncthreads();

    for (int t = 0; t < 64; ++t) {
        float4 wA[16], wB[16];

        // ---- A: h_part partials: h_part[s] = sum_h h[h] * W[h][s]
        {
            float p0 = 0.f, p1 = 0.f;
            #pragma unroll
            for (int k = 0; k < 32; ++k) {
                float w = wreg[k];
                p0 += lds[OFF_HST + hg * 32 + k] * w;        // broadcast
                p1 += lds[OFF_HST + 128 + hg * 32 + k] * w;
            }
            lds[OFF_HPP + (0 * 4 + hg) * 64 + s_] = p0;
            lds[OFF_HPP + (1 * 4 + hg) * 64 + s_] = p1;
        }
        __syncthreads();

        // chunk-0 weight prefetch: ~500cy latency hides under B + C (trans pipe)
        if (tid < 192) LOADW(wA, 0);

        // ---- B: reduce 4 row-group partials
        if (tid < 128) {
            int sq = tid >> 6, ss = tid & 63;
            lds[OFF_HPART + sq * 64 + ss] =
                  lds[OFF_HPP + (sq * 4 + 0) * 64 + ss]
                + lds[OFF_HPP + (sq * 4 + 1) * 64 + ss]
                + lds[OFF_HPP + (sq * 4 + 2) * 64 + ss]
                + lds[OFF_HPP + (sq * 4 + 3) * 64 + ss];
        }
        __syncthreads();

        // ---- C: e[hh] = sum_s tanh(h_part[s]+uproj[hh][s])*v[s]; max-free softmax
        float e = 0.f;
        {
            const float* hp = lds + OFF_HPART + seq * 64;
            #pragma unroll
            for (int s2 = 0; s2 < 64; ++s2) {
                float arg = hp[s2] + upreg[s2];
                float u2 = __expf(2.0f * arg);                   // tanh = 1 - 2/(e^{2x}+1)
                float th = 1.0f - __fdividef(2.0f, u2 + 1.0f);
                e += th * lds[OFF_VV + s2];
            }
        }
        float p = __expf(e);                 // |e| <= sum|v| ~ 5: fp32-safe
        float sm = p;
        #pragma unroll
        for (int off = 32; off >= 1; off >>= 1) sm += __shfl_xor(sm, off, 64);
        if ((tid & 63) == 0) lds[OFF_RED + 8 + hg] = sm;
        __syncthreads();
        float denom = lds[OFF_RED + 8 + seq * 2] + lds[OFF_RED + 8 + seq * 2 + 1];
        float a = __fdividef(p, denom);
        float xv = x[(size_t)(bn0 + seq) * 8192 + t * 128 + hh];
        lds[OFF_XTV + seq * 128 + hh] = a * xv;
        __syncthreads();

        // ---- D: double-buffered pipelined weight stream (8 chunks x 16 rows)
        if (tid < 192) {
            float4 a0 = make_float4(0.f, 0.f, 0.f, 0.f);
            float4 a1 = make_float4(0.f, 0.f, 0.f, 0.f);
            LOADW(wB, 1); FMACHUNK(wA, 0);
            LOADW(wA, 2); FMACHUNK(wB, 1);
            LOADW(wB, 3); FMACHUNK(wA, 2);
            LOADW(wA, 4); FMACHUNK(wB, 3);
            LOADW(wB, 5); FMACHUNK(wA, 4);
            LOADW(wA, 6); FMACHUNK(wB, 5);
            LOADW(wB, 7); FMACHUNK(wA, 6);
            FMACHUNK(wB, 7);
            *(float4*)(lds + OFF_XMRM + (dmat * 2 + 0) * 384 + dj) =
                make_float4(a0.x + dbias.x, a0.y + dbias.y, a0.z + dbias.z, a0.w + dbias.w);
            *(float4*)(lds + OFF_XMRM + (dmat * 2 + 1) * 384 + dj) =
                make_float4(a1.x + dbias.x, a1.y + dbias.y, a1.z + dbias.z, a1.w + dbias.w);
        }
        __syncthreads();

        // ---- E: gates
        {
            const float* xm = lds + OFF_XMRM + (0 * 2 + seq) * 384;
            const float* rm = lds + OFF_XMRM + (1 * 2 + seq) * 384;
            float xz = xm[hh], xr = xm[128 + hh], xh = xm[256 + hh];
            float rz = rm[hh], rr = rm[128 + hh], rh = rm[256 + hh];
            float z = __fdividef(1.0f, 1.0f + __expf(-(xz + rz)));
            float r = __fdividef(1.0f, 1.0f + __expf(-(xr + rr)));
            float hc = xh + r * rh;
            hc = hc > 0.f ? hc : 0.f;
            float hold = lds[OFF_HST + seq * 128 + hh];
            lds[OFF_HST + seq * 128 + hh] = z * hold + (1.0f - z) * hc;
        }
        __syncthreads();
    }

    out[(size_t)(bn0 + seq) * 128 + hh] = lds[OFF_HST + seq * 128 + hh];
}

extern "C" void kernel_launch(void* const* d_in, const int* in_sizes, int n_in,
                              void* d_out, int out_size, void* d_ws, size_t ws_size,
                              hipStream_t stream) {
    (void)in_sizes; (void)n_in; (void)out_size; (void)d_ws; (void)ws_size;
    const float* x      = (const float*)d_in[0];
    const float* att_v  = (const float*)d_in[1];
    const float* att_w  = (const float*)d_in[2];
    const float* att_u  = (const float*)d_in[3];
    const float* gk     = (const float*)d_in[4];
    const float* grk    = (const float*)d_in[5];
    const float* gbias  = (const float*)d_in[6];
    float* out = (float*)d_out;
    hipLaunchKernelGGL(attn_gru_kernel, dim3(256), dim3(256), 0, stream,
                       x, att_v, att_w, att_u, gk, grk, gbias, out);
}

// Round 12
// 461.746 us; speedup vs baseline: 2.1700x; 2.1700x over previous
//
#include <hip/hip_runtime.h>

// AttentionRNN: B=64, NUM=8, TC=64, H=128. bn=512 sequences.
// R12 = R9 (validated 458us) + three trims:
//  1) D chunks 32 rows (4 chunks, simple load-then-FMA -- NO manual dbuf, R11 lesson)
//     att_w moved to LDS (conflict-free under R9's A mapping) to free 32 VGPRs.
//  2) max-free softmax (R11-validated, absmax 3.8e-6): one less barrier.
//  3) x-column prefetch at loop top.
// 256 thr/block, launch_bounds(256,1), 256 blocks, 2 seqs/block.

#define OFF_ATTW  0       // [128][64] att_w (persistent)
#define OFF_U     8192    // [64][64] att_u (prologue only)
#define OFF_XMRM  12288   // [mat][seq][384]
#define OFF_HST   13824   // [2][128]
#define OFF_HPP   14080   // [2][4][64]
#define OFF_HPART 14592   // [2][64]
#define OFF_XTV   14720   // [2][128]
#define OFF_VV    14976   // [64]
#define OFF_RED   15040   // [16]
#define LDS_FLOATS 15056  // ~59 KB

#define FMA4(ACC, W, S) do { (ACC).x += (W).x*(S); (ACC).y += (W).y*(S); \
                             (ACC).z += (W).z*(S); (ACC).w += (W).w*(S); } while(0)

__global__ __launch_bounds__(256, 1)
void attn_gru_kernel(const float* __restrict__ x, const float* __restrict__ att_v,
                     const float* __restrict__ att_w, const float* __restrict__ att_u,
                     const float* __restrict__ gk, const float* __restrict__ grk,
                     const float* __restrict__ gbias, float* __restrict__ out) {
    __shared__ float lds[LDS_FLOATS];
    const int tid = threadIdx.x;
    const int bn0 = blockIdx.x * 2;

    // stage att_w, U, v; init h = 0
    for (int i = tid; i < 8192; i += 256) lds[OFF_ATTW + i] = att_w[i];
    for (int i = tid; i < 4096; i += 256) lds[OFF_U + i] = att_u[i];
    if (tid < 64) lds[OFF_VV + tid] = att_v[tid];
    lds[OFF_HST + tid] = 0.0f;
    __syncthreads();

    const int seq = tid >> 7;   // 0/1 : which of the block's 2 sequences
    const int hh  = tid & 127;  // feature index
    const int s_  = tid & 63;
    const int hg  = tid >> 6;   // 0..3 (wave id; wave-uniform)

    // per-thread uproj[seq][hh][0..63] in registers
    float upreg[64];
    #pragma unroll
    for (int s2 = 0; s2 < 64; ++s2) upreg[s2] = 0.0f;
    {
        const float* xb = x + (size_t)(bn0 + seq) * 8192 + hh;
        for (int t = 0; t < 64; ++t) {
            float xv = xb[t * 128];                  // coalesced across hh lanes
            const float* Ur = lds + OFF_U + t * 64;  // broadcast reads
            #pragma unroll
            for (int s2 = 0; s2 < 64; ++s2) upreg[s2] += xv * Ur[s2];
        }
    }

    // GRU matvec (phase D) per-thread constants: quad of weight columns
    const int col4 = tid * 4;                 // 0..764 for tid<192
    const int dmat = (col4 >= 384) ? 1 : 0;   // 0 -> gru_kernel (x_t), 1 -> gru_rkernel (h)
    const int dj   = col4 - dmat * 384;       // multiple of 4
    const float* Wm = (dmat ? grk : gk) + dj;
    const int ivoff = dmat ? OFF_HST : OFF_XTV;
    float4 dbias = make_float4(0.f, 0.f, 0.f, 0.f);
    if (tid < 192) dbias = *(const float4*)(gbias + dmat * 384 + dj);

    const float* xcol = x + (size_t)(bn0 + seq) * 8192 + hh;

    __syncthreads();

    for (int t = 0; t < 64; ++t) {
        float xv = xcol[t * 128];   // prefetch: L3 latency hides under A/B/C

        // ---- A: h_part partials: h_part[s] = sum_h h[h] * W[h][s]
        //      att_w from LDS: hg wave-uniform, s_ lane-consecutive -> conflict-free
        {
            float p0 = 0.f, p1 = 0.f;
            const float* wgl = lds + OFF_ATTW + hg * 32 * 64 + s_;
            #pragma unroll
            for (int k = 0; k < 32; ++k) {
                float w = wgl[k * 64];
                p0 += lds[OFF_HST + hg * 32 + k] * w;        // broadcast
                p1 += lds[OFF_HST + 128 + hg * 32 + k] * w;
            }
            lds[OFF_HPP + (0 * 4 + hg) * 64 + s_] = p0;
            lds[OFF_HPP + (1 * 4 + hg) * 64 + s_] = p1;
        }
        __syncthreads();

        // ---- B: reduce 4 row-group partials
        if (tid < 128) {
            int sq = tid >> 6, ss = tid & 63;
            lds[OFF_HPART + sq * 64 + ss] =
                  lds[OFF_HPP + (sq * 4 + 0) * 64 + ss]
                + lds[OFF_HPP + (sq * 4 + 1) * 64 + ss]
                + lds[OFF_HPP + (sq * 4 + 2) * 64 + ss]
                + lds[OFF_HPP + (sq * 4 + 3) * 64 + ss];
        }
        __syncthreads();

        // ---- C: e[hh] = sum_s tanh(h_part[s]+uproj[hh][s])*v[s]; max-free softmax
        float e = 0.f;
        {
            const float* hp = lds + OFF_HPART + seq * 64;
            #pragma unroll
            for (int s2 = 0; s2 < 64; ++s2) {
                float arg = hp[s2] + upreg[s2];
                float u2 = __expf(2.0f * arg);                   // tanh = 1 - 2/(e^{2x}+1)
                float th = 1.0f - __fdividef(2.0f, u2 + 1.0f);
                e += th * lds[OFF_VV + s2];
            }
        }
        float p = __expf(e);                 // |e| <= sum|v| ~ 5: fp32-safe
        float sm = p;
        #pragma unroll
        for (int off = 32; off >= 1; off >>= 1) sm += __shfl_xor(sm, off, 64);
        if ((tid & 63) == 0) lds[OFF_RED + 8 + hg] = sm;
        __syncthreads();
        float denom = lds[OFF_RED + 8 + seq * 2] + lds[OFF_RED + 8 + seq * 2 + 1];
        float a = __fdividef(p, denom);
        lds[OFF_XTV + seq * 128 + hh] = a * xv;
        __syncthreads();

        // ---- D: 4 chunks x 32 float4 weight rows, simple load-then-FMA (R9 pattern)
        if (tid < 192) {
            float4 a0 = make_float4(0.f, 0.f, 0.f, 0.f);
            float4 a1 = make_float4(0.f, 0.f, 0.f, 0.f);
            #pragma unroll 1
            for (int c = 0; c < 4; ++c) {
                float4 w[32];
                #pragma unroll
                for (int r = 0; r < 32; ++r)
                    w[r] = *(const float4*)(Wm + (size_t)(c * 32 + r) * 384);
                const float* i0 = lds + ivoff + c * 32;
                #pragma unroll
                for (int r4 = 0; r4 < 8; ++r4) {
                    float4 iA = *(const float4*)(i0 + r4 * 4);
                    float4 iB = *(const float4*)(i0 + 128 + r4 * 4);
                    FMA4(a0, w[r4*4+0], iA.x); FMA4(a1, w[r4*4+0], iB.x);
                    FMA4(a0, w[r4*4+1], iA.y); FMA4(a1, w[r4*4+1], iB.y);
                    FMA4(a0, w[r4*4+2], iA.z); FMA4(a1, w[r4*4+2], iB.z);
                    FMA4(a0, w[r4*4+3], iA.w); FMA4(a1, w[r4*4+3], iB.w);
                }
            }
            *(float4*)(lds + OFF_XMRM + (dmat * 2 + 0) * 384 + dj) =
                make_float4(a0.x + dbias.x, a0.y + dbias.y, a0.z + dbias.z, a0.w + dbias.w);
            *(float4*)(lds + OFF_XMRM + (dmat * 2 + 1) * 384 + dj) =
                make_float4(a1.x + dbias.x, a1.y + dbias.y, a1.z + dbias.z, a1.w + dbias.w);
        }
        __syncthreads();

        // ---- E: gates
        {
            const float* xm = lds + OFF_XMRM + (0 * 2 + seq) * 384;
            const float* rm = lds + OFF_XMRM + (1 * 2 + seq) * 384;
            float xz = xm[hh], xr = xm[128 + hh], xh = xm[256 + hh];
            float rz = rm[hh], rr = rm[128 + hh], rh = rm[256 + hh];
            float z = __fdividef(1.0f, 1.0f + __expf(-(xz + rz)));
            float r = __fdividef(1.0f, 1.0f + __expf(-(xr + rr)));
            float hc = xh + r * rh;
            hc = hc > 0.f ? hc : 0.f;
            float hold = lds[OFF_HST + seq * 128 + hh];
            lds[OFF_HST + seq * 128 + hh] = z * hold + (1.0f - z) * hc;
        }
        __syncthreads();
    }

    out[(size_t)(bn0 + seq) * 128 + hh] = lds[OFF_HST + seq * 128 + hh];
}

extern "C" void kernel_launch(void* const* d_in, const int* in_sizes, int n_in,
                              void* d_out, int out_size, void* d_ws, size_t ws_size,
                              hipStream_t stream) {
    (void)in_sizes; (void)n_in; (void)out_size; (void)d_ws; (void)ws_size;
    const float* x      = (const float*)d_in[0];
    const float* att_v  = (const float*)d_in[1];
    const float* att_w  = (const float*)d_in[2];
    const float* att_u  = (const float*)d_in[3];
    const float* gk     = (const float*)d_in[4];
    const float* grk    = (const float*)d_in[5];
    const float* gbias  = (const float*)d_in[6];
    float* out = (float*)d_out;
    hipLaunchKernelGGL(attn_gru_kernel, dim3(256), dim3(256), 0, stream,
                       x, att_v, att_w, att_u, gk, grk, gbias, out);
}